// Round 1
// baseline (629.529 us; speedup 1.0000x reference)
//
#include <hip/hip_runtime.h>

#define B_ 4
#define C_ 256
#define N_ 4096

typedef unsigned short u16;
typedef __bf16 bf16x8 __attribute__((ext_vector_type(8)));
typedef float f32x4 __attribute__((ext_vector_type(4)));
typedef u16 u16x8 __attribute__((ext_vector_type(8)));

union BF8 { u16x8 u; bf16x8 b; };

__device__ __forceinline__ u16 f2bf(float f) {
  unsigned int u = __float_as_uint(f);
  u += 0x7fffu + ((u >> 16) & 1u);
  return (u16)(u >> 16);
}

__device__ __forceinline__ f32x4 mfma16(bf16x8 a, bf16x8 b, f32x4 c) {
  return __builtin_amdgcn_mfma_f32_16x16x32_bf16(a, b, c, 0, 0, 0);
}

// ---------------- x[b][c][n] fp32 -> Xt[b][n][c] bf16 ----------------
__global__ __launch_bounds__(256) void k_transpose(const float* __restrict__ x,
                                                   u16* __restrict__ Xt) {
  __shared__ u16 T[64 * 72];
  const int b = blockIdx.z, c0 = blockIdx.y * 64, n0 = blockIdx.x * 64;
  const int t = threadIdx.x;
#pragma unroll
  for (int it = 0; it < 4; ++it) {
    int chunk = t + 256 * it;
    int row = chunk >> 4;   // c-local 0..63
    int col = chunk & 15;   // float4 along n
    const float* g = x + (((size_t)b * C_ + c0 + row) * N_ + n0 + col * 4);
    f32x4 v = *(const f32x4*)g;
#pragma unroll
    for (int i = 0; i < 4; ++i) T[(col * 4 + i) * 72 + row] = f2bf(v[i]);
  }
  __syncthreads();
#pragma unroll
  for (int it = 0; it < 2; ++it) {
    int chunk = t + 256 * it;
    int row = chunk >> 3;   // n-local 0..63
    int col = chunk & 7;
    *(u16x8*)&Xt[((size_t)b * N_ + n0 + row) * C_ + c0 + col * 8] =
        *(const u16x8*)&T[row * 72 + col * 8];
  }
}

// ---------------- GEMM: Y[o][n] = W[o][:] . Xt[n][:] ----------------
// MODE 0: QKV.  yo<8 -> orientation A (D[m=pix][n=o]) storing Qt/Kt[b][n][c]
//               yo>=8 -> orientation B (D[m=o][n=pix]) storing Vn[b][c][n]
// MODE 1: out-proj, orientation B, fp32 store + bias + residual.
template <int MODE>
__global__ __launch_bounds__(256) void k_gemm(
    const float* __restrict__ Wg, const float* __restrict__ bias,
    const u16* __restrict__ Bt, u16* __restrict__ Qt, u16* __restrict__ Kt,
    u16* __restrict__ Vn, const float* __restrict__ xres,
    float* __restrict__ outp) {
  __shared__ u16 Xs[64 * 264];
  const int b = blockIdx.z, yo = blockIdx.y, n0 = blockIdx.x * 64;
  const int t = threadIdx.x, w = t >> 6, lane = t & 63, quad = lane >> 4,
            l16 = lane & 15;
#pragma unroll
  for (int it = 0; it < 8; ++it) {
    int chunk = t + 256 * it;
    int row = chunk >> 5, col = chunk & 31;
    *(u16x8*)&Xs[row * 264 + col * 8] =
        *(const u16x8*)&Bt[((size_t)b * N_ + n0 + row) * C_ + col * 8];
  }
  __syncthreads();

  f32x4 acc[4];
#pragma unroll
  for (int jt = 0; jt < 4; ++jt) acc[jt] = (f32x4){0.f, 0.f, 0.f, 0.f};

  if (MODE == 0 && yo < 8) {
    // A = Xt rows (LDS), B = W^T (global fp32 -> bf16)
    BF8 afr[8];
    const u16* arow = &Xs[(w * 16 + l16) * 264 + quad * 8];
#pragma unroll
    for (int ks = 0; ks < 8; ++ks) afr[ks].u = *(const u16x8*)(arow + ks * 32);
#pragma unroll
    for (int jt = 0; jt < 4; ++jt) {
      const float* wrow = Wg + (size_t)(yo * 64 + 16 * jt + l16) * C_ + quad * 8;
#pragma unroll
      for (int ks = 0; ks < 8; ++ks) {
        f32x4 w0 = *(const f32x4*)(wrow + ks * 32);
        f32x4 w1 = *(const f32x4*)(wrow + ks * 32 + 4);
        BF8 bf;
#pragma unroll
        for (int i = 0; i < 4; ++i) {
          bf.u[i] = f2bf(w0[i]);
          bf.u[4 + i] = f2bf(w1[i]);
        }
        acc[jt] = mfma16(afr[ks].b, bf.b, acc[jt]);
      }
    }
    const float mult = (yo < 4) ? 0.0625f : 1.0f;  // fold softmax scale into Q
    u16* dst = (yo < 4) ? Qt : Kt;
    const int olocal = (yo < 4) ? yo * 64 : yo * 64 - 256;
#pragma unroll
    for (int jt = 0; jt < 4; ++jt) {
      float bv = bias[yo * 64 + 16 * jt + l16];
#pragma unroll
      for (int r = 0; r < 4; ++r) {
        float v = (acc[jt][r] + bv) * mult;
        int ip = n0 + w * 16 + quad * 4 + r;
        dst[((size_t)b * N_ + ip) * C_ + olocal + 16 * jt + l16] = f2bf(v);
      }
    }
  } else {
    // A = W rows (global fp32 -> bf16), B = Xt (LDS)
    const int o0 = (MODE == 0) ? (yo - 8) * 64 + 512 : yo * 64;
    BF8 afr[8];
    const float* wrow = Wg + (size_t)(o0 + w * 16 + l16) * C_ + quad * 8;
#pragma unroll
    for (int ks = 0; ks < 8; ++ks) {
      f32x4 w0 = *(const f32x4*)(wrow + ks * 32);
      f32x4 w1 = *(const f32x4*)(wrow + ks * 32 + 4);
#pragma unroll
      for (int i = 0; i < 4; ++i) {
        afr[ks].u[i] = f2bf(w0[i]);
        afr[ks].u[4 + i] = f2bf(w1[i]);
      }
    }
#pragma unroll
    for (int jt = 0; jt < 4; ++jt) {
#pragma unroll
      for (int ks = 0; ks < 8; ++ks) {
        BF8 bfr;
        bfr.u = *(const u16x8*)&Xs[(16 * jt + l16) * 264 + ks * 32 + quad * 8];
        acc[jt] = mfma16(afr[ks].b, bfr.b, acc[jt]);
      }
    }
    float bv[4];
#pragma unroll
    for (int r = 0; r < 4; ++r) bv[r] = bias[o0 + w * 16 + quad * 4 + r];
    if (MODE == 0) {
#pragma unroll
      for (int jt = 0; jt < 4; ++jt)
#pragma unroll
        for (int r = 0; r < 4; ++r) {
          int cv = o0 - 512 + w * 16 + quad * 4 + r;
          int pix = n0 + 16 * jt + l16;
          Vn[((size_t)b * C_ + cv) * N_ + pix] = f2bf(acc[jt][r] + bv[r]);
        }
    } else {
#pragma unroll
      for (int jt = 0; jt < 4; ++jt)
#pragma unroll
        for (int r = 0; r < 4; ++r) {
          int oc = o0 + w * 16 + quad * 4 + r;
          int pix = n0 + 16 * jt + l16;
          size_t idx = ((size_t)b * C_ + oc) * N_ + pix;
          outp[idx] = acc[jt][r] + bv[r] + xres[idx];
        }
    }
  }
}

// ---------------- flash attention: Qt,Kt [b][n][c], Vn [b][c][n] -> At [b][n][c]
__global__ __launch_bounds__(256) void k_attn(const u16* __restrict__ Qt,
                                              const u16* __restrict__ Kt,
                                              const u16* __restrict__ Vn,
                                              u16* __restrict__ At) {
  __shared__ u16 Ks[64 * 136];   // [j][c-half 128 + pad]
  __shared__ u16 Vs[256 * 72];   // [c][j 64 + pad]
  __shared__ u16 Ps[64 * 72];    // [m][j 64 + pad], wave-private rows
  const int b = blockIdx.y, i0 = blockIdx.x * 64;
  const int t = threadIdx.x, w = t >> 6, lane = t & 63, quad = lane >> 4,
            l16 = lane & 15;

  BF8 qf[8];
  {
    const u16* qrow = Qt + ((size_t)b * N_ + i0 + w * 16 + l16) * C_ + quad * 8;
#pragma unroll
    for (int ks = 0; ks < 8; ++ks) qf[ks].u = *(const u16x8*)(qrow + ks * 32);
  }
  f32x4 o[16];
#pragma unroll
  for (int ct = 0; ct < 16; ++ct) o[ct] = (f32x4){0.f, 0.f, 0.f, 0.f};
  float m_i[4], l_i[4];
#pragma unroll
  for (int r = 0; r < 4; ++r) {
    m_i[r] = -__builtin_inff();
    l_i[r] = 0.f;
  }

  const u16* kbase = Kt + (size_t)b * N_ * C_;
  const u16* vbase = Vn + (size_t)b * (size_t)C_ * N_;
  const float LOG2E = 1.4426950408889634f;

  for (int j0 = 0; j0 < N_; j0 += 64) {
    __syncthreads();  // prior-iteration LDS reads done
#pragma unroll
    for (int it = 0; it < 8; ++it) {  // stage V tile [256 c][64 j]
      int chunk = t + 256 * it;
      int row = chunk >> 3, col = chunk & 7;
      *(u16x8*)&Vs[row * 72 + col * 8] =
          *(const u16x8*)&vbase[(size_t)row * N_ + j0 + col * 8];
    }
#pragma unroll
    for (int it = 0; it < 4; ++it) {  // stage K tile, c-half 0
      int chunk = t + 256 * it;
      int row = chunk >> 4, col = chunk & 15;
      *(u16x8*)&Ks[row * 136 + col * 8] =
          *(const u16x8*)&kbase[(size_t)(j0 + row) * C_ + col * 8];
    }
    __syncthreads();

    f32x4 s[4];
#pragma unroll
    for (int jt = 0; jt < 4; ++jt) s[jt] = (f32x4){0.f, 0.f, 0.f, 0.f};
#pragma unroll
    for (int jt = 0; jt < 4; ++jt)
#pragma unroll
      for (int ks = 0; ks < 4; ++ks) {
        BF8 kf;
        kf.u = *(const u16x8*)&Ks[(16 * jt + l16) * 136 + ks * 32 + quad * 8];
        s[jt] = mfma16(qf[ks].b, kf.b, s[jt]);
      }
    __syncthreads();
#pragma unroll
    for (int it = 0; it < 4; ++it) {  // stage K tile, c-half 1
      int chunk = t + 256 * it;
      int row = chunk >> 4, col = chunk & 15;
      *(u16x8*)&Ks[row * 136 + col * 8] =
          *(const u16x8*)&kbase[(size_t)(j0 + row) * C_ + 128 + col * 8];
    }
    __syncthreads();
#pragma unroll
    for (int jt = 0; jt < 4; ++jt)
#pragma unroll
      for (int ks = 0; ks < 4; ++ks) {
        BF8 kf;
        kf.u = *(const u16x8*)&Ks[(16 * jt + l16) * 136 + ks * 32 + quad * 8];
        s[jt] = mfma16(qf[4 + ks].b, kf.b, s[jt]);
      }

    // online softmax; rows m = quad*4+r, 16 j-lanes x 4 jt tiles
    float mx[4];
#pragma unroll
    for (int r = 0; r < 4; ++r)
      mx[r] = fmaxf(fmaxf(s[0][r], s[1][r]), fmaxf(s[2][r], s[3][r]));
#pragma unroll
    for (int off = 8; off >= 1; off >>= 1)
#pragma unroll
      for (int r = 0; r < 4; ++r) mx[r] = fmaxf(mx[r], __shfl_xor(mx[r], off));
    float alpha[4];
#pragma unroll
    for (int r = 0; r < 4; ++r) {
      float mn = fmaxf(m_i[r], mx[r]);
      alpha[r] = exp2f((m_i[r] - mn) * LOG2E);
      m_i[r] = mn;
    }
    float psum[4] = {0.f, 0.f, 0.f, 0.f};
#pragma unroll
    for (int jt = 0; jt < 4; ++jt)
#pragma unroll
      for (int r = 0; r < 4; ++r) {
        float p = exp2f((s[jt][r] - m_i[r]) * LOG2E);
        psum[r] += p;
        Ps[(w * 16 + quad * 4 + r) * 72 + 16 * jt + l16] = f2bf(p);
      }
#pragma unroll
    for (int off = 8; off >= 1; off >>= 1)
#pragma unroll
      for (int r = 0; r < 4; ++r) psum[r] += __shfl_xor(psum[r], off);
#pragma unroll
    for (int r = 0; r < 4; ++r) l_i[r] = l_i[r] * alpha[r] + psum[r];
#pragma unroll
    for (int ct = 0; ct < 16; ++ct)
#pragma unroll
      for (int r = 0; r < 4; ++r) o[ct][r] *= alpha[r];

    // O += P.V  (P from wave-private LDS rows; V_lds is [c][j])
#pragma unroll
    for (int ks2 = 0; ks2 < 2; ++ks2) {
      BF8 pf;
      pf.u = *(const u16x8*)&Ps[(w * 16 + l16) * 72 + ks2 * 32 + quad * 8];
#pragma unroll
      for (int ct = 0; ct < 16; ++ct) {
        BF8 vf;
        vf.u = *(const u16x8*)&Vs[(16 * ct + l16) * 72 + ks2 * 32 + quad * 8];
        o[ct] = mfma16(pf.b, vf.b, o[ct]);
      }
    }
  }

  float inv[4];
#pragma unroll
  for (int r = 0; r < 4; ++r) inv[r] = 1.0f / l_i[r];
#pragma unroll
  for (int ct = 0; ct < 16; ++ct)
#pragma unroll
    for (int r = 0; r < 4; ++r) {
      int ip = i0 + w * 16 + quad * 4 + r;
      At[((size_t)b * N_ + ip) * C_ + 16 * ct + l16] = f2bf(o[ct][r] * inv[r]);
    }
}

extern "C" void kernel_launch(void* const* d_in, const int* in_sizes, int n_in,
                              void* d_out, int out_size, void* d_ws,
                              size_t ws_size, hipStream_t stream) {
  (void)in_sizes; (void)n_in; (void)out_size; (void)ws_size;
  const float* x = (const float*)d_in[0];
  const float* w_qkv = (const float*)d_in[1];
  const float* b_qkv = (const float*)d_in[2];
  const float* w_out = (const float*)d_in[3];
  const float* b_out = (const float*)d_in[4];
  float* outp = (float*)d_out;

  const size_t TENS = (size_t)B_ * N_ * C_;  // 4M elems
  u16* Xt = (u16*)d_ws;      // [B][N][C] bf16
  u16* Qt = Xt + TENS;       // [B][N][C] bf16 (scaled by 1/16)
  u16* Kt = Qt + TENS;       // [B][N][C] bf16
  u16* Vn = Kt + TENS;       // [B][C][N] bf16
  u16* At = Vn + TENS;       // [B][N][C] bf16
  // total workspace use: 5 * 8 MiB = 40 MiB

  k_transpose<<<dim3(64, 4, 4), 256, 0, stream>>>(x, Xt);
  k_gemm<0><<<dim3(64, 12, 4), 256, 0, stream>>>(w_qkv, b_qkv, Xt, Qt, Kt, Vn,
                                                 nullptr, nullptr);
  k_attn<<<dim3(64, 4), 256, 0, stream>>>(Qt, Kt, Vn, At);
  k_gemm<1><<<dim3(64, 4, 4), 256, 0, stream>>>(w_out, b_out, At, nullptr,
                                                nullptr, nullptr, x, outp);
}

// Round 2
// 365.194 us; speedup vs baseline: 1.7238x; 1.7238x over previous
//
#include <hip/hip_runtime.h>

#define B_ 4
#define C_ 256
#define N_ 4096

typedef unsigned short u16;
typedef __bf16 bf16x8 __attribute__((ext_vector_type(8)));
typedef float f32x4 __attribute__((ext_vector_type(4)));
typedef u16 u16x8 __attribute__((ext_vector_type(8)));

union BF8 { u16x8 u; bf16x8 b; };

__device__ __forceinline__ u16 f2bf(float f) {
  unsigned int u = __float_as_uint(f);
  u += 0x7fffu + ((u >> 16) & 1u);
  return (u16)(u >> 16);
}
__device__ __forceinline__ float bf2f(u16 u) {
  return __uint_as_float(((unsigned int)u) << 16);
}

__device__ __forceinline__ f32x4 mfma16(bf16x8 a, bf16x8 b, f32x4 c) {
  return __builtin_amdgcn_mfma_f32_16x16x32_bf16(a, b, c, 0, 0, 0);
}

// ---------------- x[b][c][n] fp32 -> Xt[b][n][c] bf16 ----------------
__global__ __launch_bounds__(256) void k_transpose(const float* __restrict__ x,
                                                   u16* __restrict__ Xt) {
  __shared__ u16 T[64 * 72];
  const int b = blockIdx.z, c0 = blockIdx.y * 64, n0 = blockIdx.x * 64;
  const int t = threadIdx.x;
#pragma unroll
  for (int it = 0; it < 4; ++it) {
    int chunk = t + 256 * it;
    int row = chunk >> 4;   // c-local 0..63
    int col = chunk & 15;   // float4 along n
    const float* g = x + (((size_t)b * C_ + c0 + row) * N_ + n0 + col * 4);
    f32x4 v = *(const f32x4*)g;
#pragma unroll
    for (int i = 0; i < 4; ++i) T[(col * 4 + i) * 72 + row] = f2bf(v[i]);
  }
  __syncthreads();
#pragma unroll
  for (int it = 0; it < 2; ++it) {
    int chunk = t + 256 * it;
    int row = chunk >> 3;   // n-local 0..63
    int col = chunk & 7;
    *(u16x8*)&Xt[((size_t)b * N_ + n0 + row) * C_ + c0 + col * 8] =
        *(const u16x8*)&T[row * 72 + col * 8];
  }
}

// ---------------- GEMM: Y[o][n] = W[o][:] . Xt[n][:] ----------------
template <int MODE>
__global__ __launch_bounds__(256) void k_gemm(
    const float* __restrict__ Wg, const float* __restrict__ bias,
    const u16* __restrict__ Bt, u16* __restrict__ Qt, u16* __restrict__ Kt,
    u16* __restrict__ Vn, const float* __restrict__ xres,
    float* __restrict__ outp) {
  __shared__ u16 Xs[64 * 264];
  const int b = blockIdx.z, yo = blockIdx.y, n0 = blockIdx.x * 64;
  const int t = threadIdx.x, w = t >> 6, lane = t & 63, quad = lane >> 4,
            l16 = lane & 15;
#pragma unroll
  for (int it = 0; it < 8; ++it) {
    int chunk = t + 256 * it;
    int row = chunk >> 5, col = chunk & 31;
    *(u16x8*)&Xs[row * 264 + col * 8] =
        *(const u16x8*)&Bt[((size_t)b * N_ + n0 + row) * C_ + col * 8];
  }
  __syncthreads();

  f32x4 acc[4];
#pragma unroll
  for (int jt = 0; jt < 4; ++jt) acc[jt] = (f32x4){0.f, 0.f, 0.f, 0.f};

  if (MODE == 0 && yo < 8) {
    BF8 afr[8];
    const u16* arow = &Xs[(w * 16 + l16) * 264 + quad * 8];
#pragma unroll
    for (int ks = 0; ks < 8; ++ks) afr[ks].u = *(const u16x8*)(arow + ks * 32);
#pragma unroll
    for (int jt = 0; jt < 4; ++jt) {
      const float* wrow = Wg + (size_t)(yo * 64 + 16 * jt + l16) * C_ + quad * 8;
#pragma unroll
      for (int ks = 0; ks < 8; ++ks) {
        f32x4 w0 = *(const f32x4*)(wrow + ks * 32);
        f32x4 w1 = *(const f32x4*)(wrow + ks * 32 + 4);
        BF8 bf;
#pragma unroll
        for (int i = 0; i < 4; ++i) {
          bf.u[i] = f2bf(w0[i]);
          bf.u[4 + i] = f2bf(w1[i]);
        }
        acc[jt] = mfma16(afr[ks].b, bf.b, acc[jt]);
      }
    }
    const float mult = (yo < 4) ? 0.0625f : 1.0f;  // fold softmax scale into Q
    u16* dst = (yo < 4) ? Qt : Kt;
    const int olocal = (yo < 4) ? yo * 64 : yo * 64 - 256;
#pragma unroll
    for (int jt = 0; jt < 4; ++jt) {
      float bv = bias[yo * 64 + 16 * jt + l16];
#pragma unroll
      for (int r = 0; r < 4; ++r) {
        float v = (acc[jt][r] + bv) * mult;
        int ip = n0 + w * 16 + quad * 4 + r;
        dst[((size_t)b * N_ + ip) * C_ + olocal + 16 * jt + l16] = f2bf(v);
      }
    }
  } else {
    const int o0 = (MODE == 0) ? (yo - 8) * 64 + 512 : yo * 64;
    BF8 afr[8];
    const float* wrow = Wg + (size_t)(o0 + w * 16 + l16) * C_ + quad * 8;
#pragma unroll
    for (int ks = 0; ks < 8; ++ks) {
      f32x4 w0 = *(const f32x4*)(wrow + ks * 32);
      f32x4 w1 = *(const f32x4*)(wrow + ks * 32 + 4);
#pragma unroll
      for (int i = 0; i < 4; ++i) {
        afr[ks].u[i] = f2bf(w0[i]);
        afr[ks].u[4 + i] = f2bf(w1[i]);
      }
    }
#pragma unroll
    for (int jt = 0; jt < 4; ++jt) {
#pragma unroll
      for (int ks = 0; ks < 8; ++ks) {
        BF8 bfr;
        bfr.u = *(const u16x8*)&Xs[(16 * jt + l16) * 264 + ks * 32 + quad * 8];
        acc[jt] = mfma16(afr[ks].b, bfr.b, acc[jt]);
      }
    }
    float bv[4];
#pragma unroll
    for (int r = 0; r < 4; ++r) bv[r] = bias[o0 + w * 16 + quad * 4 + r];
    if (MODE == 0) {
#pragma unroll
      for (int jt = 0; jt < 4; ++jt)
#pragma unroll
        for (int r = 0; r < 4; ++r) {
          int cv = o0 - 512 + w * 16 + quad * 4 + r;
          int pix = n0 + 16 * jt + l16;
          Vn[((size_t)b * C_ + cv) * N_ + pix] = f2bf(acc[jt][r] + bv[r]);
        }
    } else {
#pragma unroll
      for (int jt = 0; jt < 4; ++jt)
#pragma unroll
        for (int r = 0; r < 4; ++r) {
          int oc = o0 + w * 16 + quad * 4 + r;
          int pix = n0 + 16 * jt + l16;
          size_t idx = ((size_t)b * C_ + oc) * N_ + pix;
          outp[idx] = acc[jt][r] + bv[r] + xres[idx];
        }
    }
  }
}

// ---------------- flash attention, 2-way j-split, XCD-batch-local ----------
// grid: 512 blocks 1-D. xcd = id&7 -> b = xcd>>1, jhalf = xcd&1 (keeps each
// XCD's KV working set = one batch half ~2MB inside its 4MB L2).
// Writes unnormalized partial O (bf16) + (m,l) per row per split.
__global__ __launch_bounds__(256) void k_attn(const u16* __restrict__ Qt,
                                              const u16* __restrict__ Kt,
                                              const u16* __restrict__ Vn,
                                              u16* __restrict__ Op,
                                              float2* __restrict__ Ml) {
  __shared__ u16 Ks[64 * 264];   // [j][c 256 + pad]  33 KB
  __shared__ u16 Vs[256 * 72];   // [c][j 64 + pad]   36 KB
  __shared__ u16 Ps[64 * 72];    // [m][j 64 + pad]    9 KB  (total 78 KB)
  const int id = blockIdx.x;
  const int xcd = id & 7;
  const int b = xcd >> 1;
  const int jh = xcd & 1;
  const int i0 = (id >> 3) * 64;
  const int t = threadIdx.x, w = t >> 6, lane = t & 63, quad = lane >> 4,
            l16 = lane & 15;

  BF8 qf[8];
  {
    const u16* qrow = Qt + ((size_t)b * N_ + i0 + w * 16 + l16) * C_ + quad * 8;
#pragma unroll
    for (int ks = 0; ks < 8; ++ks) qf[ks].u = *(const u16x8*)(qrow + ks * 32);
  }
  f32x4 o[16];
#pragma unroll
  for (int ct = 0; ct < 16; ++ct) o[ct] = (f32x4){0.f, 0.f, 0.f, 0.f};
  float m_i[4], l_i[4];
#pragma unroll
  for (int r = 0; r < 4; ++r) {
    m_i[r] = -__builtin_inff();
    l_i[r] = 0.f;
  }

  const u16* kbase = Kt + (size_t)b * N_ * C_;
  const u16* vbase = Vn + (size_t)b * (size_t)C_ * N_;
  const float LOG2E = 1.4426950408889634f;
  const int jbeg = jh * (N_ / 2), jend = jbeg + N_ / 2;

  for (int j0 = jbeg; j0 < jend; j0 += 64) {
    __syncthreads();  // prior-iteration LDS reads done
#pragma unroll
    for (int it = 0; it < 8; ++it) {  // stage V tile [256 c][64 j]
      int chunk = t + 256 * it;
      int row = chunk >> 3, col = chunk & 7;
      *(u16x8*)&Vs[row * 72 + col * 8] =
          *(const u16x8*)&vbase[(size_t)row * N_ + j0 + col * 8];
    }
#pragma unroll
    for (int it = 0; it < 8; ++it) {  // stage K tile [64 j][256 c]
      int chunk = t + 256 * it;
      int row = chunk >> 5, col = chunk & 31;
      *(u16x8*)&Ks[row * 264 + col * 8] =
          *(const u16x8*)&kbase[(size_t)(j0 + row) * C_ + col * 8];
    }
    __syncthreads();

    f32x4 s[4];
#pragma unroll
    for (int jt = 0; jt < 4; ++jt) s[jt] = (f32x4){0.f, 0.f, 0.f, 0.f};
#pragma unroll
    for (int jt = 0; jt < 4; ++jt)
#pragma unroll
      for (int ks = 0; ks < 8; ++ks) {
        BF8 kf;
        kf.u = *(const u16x8*)&Ks[(16 * jt + l16) * 264 + ks * 32 + quad * 8];
        s[jt] = mfma16(qf[ks].b, kf.b, s[jt]);
      }

    // online softmax; rows m = quad*4+r
    float mx[4];
#pragma unroll
    for (int r = 0; r < 4; ++r)
      mx[r] = fmaxf(fmaxf(s[0][r], s[1][r]), fmaxf(s[2][r], s[3][r]));
#pragma unroll
    for (int off = 8; off >= 1; off >>= 1)
#pragma unroll
      for (int r = 0; r < 4; ++r) mx[r] = fmaxf(mx[r], __shfl_xor(mx[r], off));
    float alpha[4];
#pragma unroll
    for (int r = 0; r < 4; ++r) {
      float mn = fmaxf(m_i[r], mx[r]);
      alpha[r] = exp2f((m_i[r] - mn) * LOG2E);
      m_i[r] = mn;
    }
    float psum[4] = {0.f, 0.f, 0.f, 0.f};
#pragma unroll
    for (int jt = 0; jt < 4; ++jt)
#pragma unroll
      for (int r = 0; r < 4; ++r) {
        float p = exp2f((s[jt][r] - m_i[r]) * LOG2E);
        psum[r] += p;
        Ps[(w * 16 + quad * 4 + r) * 72 + 16 * jt + l16] = f2bf(p);
      }
#pragma unroll
    for (int off = 8; off >= 1; off >>= 1)
#pragma unroll
      for (int r = 0; r < 4; ++r) psum[r] += __shfl_xor(psum[r], off);
#pragma unroll
    for (int r = 0; r < 4; ++r) l_i[r] = l_i[r] * alpha[r] + psum[r];
#pragma unroll
    for (int ct = 0; ct < 16; ++ct)
#pragma unroll
      for (int r = 0; r < 4; ++r) o[ct][r] *= alpha[r];

    // O += P.V  (P wave-private LDS rows; V_lds is [c][j])
#pragma unroll
    for (int ks2 = 0; ks2 < 2; ++ks2) {
      BF8 pf;
      pf.u = *(const u16x8*)&Ps[(w * 16 + l16) * 72 + ks2 * 32 + quad * 8];
#pragma unroll
      for (int ct = 0; ct < 16; ++ct) {
        BF8 vf;
        vf.u = *(const u16x8*)&Vs[(16 * ct + l16) * 72 + ks2 * 32 + quad * 8];
        o[ct] = mfma16(pf.b, vf.b, o[ct]);
      }
    }
  }

  // write unnormalized partial O (bf16) + (m,l)
  u16* op = Op + ((size_t)jh * B_ + b) * (size_t)N_ * C_;
  float2* ml = Ml + ((size_t)jh * B_ + b) * N_;
#pragma unroll
  for (int r = 0; r < 4; ++r) {
    int ip = i0 + w * 16 + quad * 4 + r;
    if (l16 == 0 && r == 0) {}  // no-op keep shape
    if (quad == (lane >> 4)) {}  // no-op
    if (l16 < 1) ml[ip] = make_float2(m_i[r], l_i[r]);
  }
#pragma unroll
  for (int ct = 0; ct < 16; ++ct)
#pragma unroll
    for (int r = 0; r < 4; ++r) {
      int ip = i0 + w * 16 + quad * 4 + r;
      op[(size_t)ip * C_ + 16 * ct + l16] = f2bf(o[ct][r]);
    }
}

// ---------------- merge the 2 j-split partials -> At[b][n][c] bf16 --------
__global__ __launch_bounds__(256) void k_combine(const u16* __restrict__ Op,
                                                 const float2* __restrict__ Ml,
                                                 u16* __restrict__ At) {
  const size_t TEN = (size_t)B_ * N_ * C_;
  const int idx = blockIdx.x * 256 + threadIdx.x;
  const size_t base = (size_t)idx * 8;
  const int row = (int)(base >> 8);  // b*N + n
  float2 ml0 = Ml[row];
  float2 ml1 = Ml[B_ * N_ + row];
  const float LOG2E = 1.4426950408889634f;
  float m = fmaxf(ml0.x, ml1.x);
  float w0 = exp2f((ml0.x - m) * LOG2E);
  float w1 = exp2f((ml1.x - m) * LOG2E);
  float denom = w0 * ml0.y + w1 * ml1.y;
  float f0 = w0 / denom, f1 = w1 / denom;
  u16x8 a0 = *(const u16x8*)&Op[base];
  u16x8 a1 = *(const u16x8*)&Op[TEN + base];
  u16x8 r;
#pragma unroll
  for (int i = 0; i < 8; ++i) r[i] = f2bf(f0 * bf2f(a0[i]) + f1 * bf2f(a1[i]));
  *(u16x8*)&At[base] = r;
}

extern "C" void kernel_launch(void* const* d_in, const int* in_sizes, int n_in,
                              void* d_out, int out_size, void* d_ws,
                              size_t ws_size, hipStream_t stream) {
  (void)in_sizes; (void)n_in; (void)out_size; (void)ws_size;
  const float* x = (const float*)d_in[0];
  const float* w_qkv = (const float*)d_in[1];
  const float* b_qkv = (const float*)d_in[2];
  const float* w_out = (const float*)d_in[3];
  const float* b_out = (const float*)d_in[4];
  float* outp = (float*)d_out;

  const size_t TENS = (size_t)B_ * N_ * C_;  // 4M elems
  u16* Xt = (u16*)d_ws;      // [B][N][C] bf16            8 MB
  u16* Qt = Xt + TENS;       // [B][N][C] bf16 (q/16)     8 MB
  u16* Kt = Qt + TENS;       // [B][N][C] bf16            8 MB
  u16* Vn = Kt + TENS;       // [B][C][N] bf16            8 MB
  u16* At = Vn + TENS;       // [B][N][C] bf16            8 MB
  u16* Op = At + TENS;       // [2][B][N][C] bf16        16 MB
  float2* Ml = (float2*)(Op + 2 * TENS);  // [2][B][N]   256 KB
  // total workspace use ~56.5 MB

  k_transpose<<<dim3(64, 4, 4), 256, 0, stream>>>(x, Xt);
  k_gemm<0><<<dim3(64, 12, 4), 256, 0, stream>>>(w_qkv, b_qkv, Xt, Qt, Kt, Vn,
                                                 nullptr, nullptr);
  k_attn<<<dim3(512), 256, 0, stream>>>(Qt, Kt, Vn, Op, Ml);
  k_combine<<<dim3((int)(TENS / 2048)), 256, 0, stream>>>(Op, Ml, At);
  k_gemm<1><<<dim3(64, 4, 4), 256, 0, stream>>>(w_out, b_out, At, nullptr,
                                                nullptr, nullptr, x, outp);
}